// Round 6
// baseline (3361.569 us; speedup 1.0000x reference)
//
#include <hip/hip_runtime.h>
#include <math.h>

#define Hd 512
#define Bd 64
#define Pd 32
#define Rd 4
#define Wd 64

typedef _Float16 h2v __attribute__((ext_vector_type(2)));

__device__ __forceinline__ float tanh_fast(float x) {
    float e = __expf(x + x);
    return 1.f - __fdividef(2.f, 1.f + e);
}

__device__ __forceinline__ float d2(unsigned a, unsigned b, float c) {
    return __builtin_amdgcn_fdot2(__builtin_bit_cast(h2v, a),
                                  __builtin_bit_cast(h2v, b), c, false);
}

__device__ __forceinline__ unsigned pk(float a, float b) {
    h2v p; p.x = (_Float16)a; p.y = (_Float16)b;
    return __builtin_bit_cast(unsigned, p);
}

// ---- build WAp = fp16-packed [W_a | lin_w^T] (256 h2 x 1024) + Wtp (256 h2 x 512) ----
__global__ __launch_bounds__(256) void k_prep(const float* __restrict__ Wa,
                                              const float* __restrict__ lin_w,
                                              const float* __restrict__ Wt,
                                              unsigned* __restrict__ WAp,
                                              unsigned* __restrict__ Wtp) {
    __shared__ unsigned tile[32][33];
    int bx = blockIdx.x, by = blockIdx.y;           // bx: 16 c-tiles, by: 8 h2-tiles
    int lane = threadIdx.x & 31, ty = threadIdx.x >> 5;
    // part A: W_a columns 0..511, packed along h
    for (int k = 0; k < 32; k += 8) {
        int h2 = by * 32 + ty + k, c = bx * 32 + lane;
        WAp[(size_t)h2 * 1024 + c] = pk(Wa[(size_t)(2 * h2) * Hd + c],
                                        Wa[(size_t)(2 * h2 + 1) * Hd + c]);
        Wtp[(size_t)h2 * 512 + c]  = pk(Wt[(size_t)(2 * h2) * Hd + c],
                                        Wt[(size_t)(2 * h2 + 1) * Hd + c]);
    }
    // part B: lin_w^T -> columns 512..1023 (transpose via LDS)
    for (int k = 0; k < 32; k += 8) {
        int c_src = bx * 32 + ty + k, h2 = by * 32 + lane;
        float2 v = *(const float2*)&lin_w[(size_t)c_src * Hd + 2 * h2];
        tile[ty + k][lane] = pk(v.x, v.y);
    }
    __syncthreads();
    for (int k = 0; k < 32; k += 8) {
        int h2o = by * 32 + ty + k, co = bx * 32 + lane;
        WAp[(size_t)h2o * 1024 + 512 + co] = tile[lane][ty + k];
    }
}

// ---------------- Wctx[b,p,k] = sum_h ctx[b,p,h] * Wc[h,k]  (32 rows/block) ----------------
__global__ __launch_bounds__(256) void k_wctx(const float* __restrict__ ctx_pbh,
                                              const float* __restrict__ Wc,
                                              float* __restrict__ Wctx) {
    __shared__ float As[32][Hd];
    int r0 = blockIdx.x * 32;
    int tid = threadIdx.x;
    for (int rr = 0; rr < 32; ++rr) {
        int bp = r0 + rr;
        int b = bp >> 5, p = bp & 31;
        const float* src = ctx_pbh + ((size_t)p * Bd + b) * Hd;
        for (int h = tid; h < Hd; h += 256) As[rr][h] = src[h];
    }
    __syncthreads();
    int c0 = tid, c1 = tid + 256;
    float acc0[32], acc1[32];
    #pragma unroll
    for (int rr = 0; rr < 32; ++rr) { acc0[rr] = 0.f; acc1[rr] = 0.f; }
    for (int h = 0; h < Hd; ++h) {
        float w0 = Wc[(size_t)h * Hd + c0], w1 = Wc[(size_t)h * Hd + c1];
        #pragma unroll
        for (int rr = 0; rr < 32; ++rr) {
            float a = As[rr][h];
            acc0[rr] += a * w0;
            acc1[rr] += a * w1;
        }
    }
    for (int rr = 0; rr < 32; ++rr) {
        Wctx[(size_t)(r0 + rr) * Hd + c0] = acc0[rr];
        Wctx[(size_t)(r0 + rr) * Hd + c1] = acc1[rr];
    }
}

// ---------------- rwh[t*256+row][c] = fp16(sum_h resp * Wt), fp16 dot2 path ----------------
__global__ __launch_bounds__(512) void k_rw(const float* __restrict__ resp,
                                            const unsigned* __restrict__ Wtp,
                                            unsigned short* __restrict__ rwh) {
    __shared__ unsigned As[32 * 256];      // 32 rows x 256 h2, packed fp16
    int gr0 = blockIdx.x * 32, tid = threadIdx.x;
    for (int i = tid; i < 32 * 256; i += 512) {
        int rr = i >> 8, h2 = i & 255;
        int gr = gr0 + rr;
        int t = gr >> 8, row = gr & 255, r = row >> 6, bb = row & 63;
        float2 v = *(const float2*)(resp + (((size_t)(r * Wd + t)) * Bd + bb) * Hd + (h2 << 1));
        As[i] = pk(v.x, v.y);
    }
    __syncthreads();
    float acc[32];
    #pragma unroll
    for (int rr = 0; rr < 32; ++rr) acc[rr] = 0.f;
    const int c = tid;
    #pragma unroll 1
    for (int h2 = 0; h2 < 256; h2 += 4) {
        unsigned w0 = Wtp[((h2 + 0) << 9) + c];
        unsigned w1 = Wtp[((h2 + 1) << 9) + c];
        unsigned w2 = Wtp[((h2 + 2) << 9) + c];
        unsigned w3 = Wtp[((h2 + 3) << 9) + c];
        #pragma unroll
        for (int rr = 0; rr < 32; ++rr) {
            uint4 a4 = *(const uint4*)&As[(rr << 8) + h2];
            float s = acc[rr];
            s = d2(a4.x, w0, s); s = d2(a4.y, w1, s);
            s = d2(a4.z, w2, s); s = d2(a4.w, w3, s);
            acc[rr] = s;
        }
    }
    for (int rr = 0; rr < 32; ++rr)
        rwh[((size_t)(gr0 + rr) << 9) + c] =
            __builtin_bit_cast(unsigned short, (_Float16)acc[rr]);
}

// ---------------- cooperative scan: 256 blocks = 64 b-groups x 4 column-slices ----------------
// Block (b, j): GEMM computes w[r=0..3][j*256 .. j*256+255] (stream = 256 KB/step, 4x less),
// slices exchanged via w_glob; B/C/D done for own row r=j; atten exchanged via atten_glob.
// Sync = per-group monotonic counters (4 arrivals/step each), not a grid barrier.
__global__ __launch_bounds__(1024, 4) void k_scan(
    const float* __restrict__ ctx,      // (P,B,H)
    const unsigned short* __restrict__ rwh, // (W*256, H) fp16
    const unsigned* __restrict__ WAp,   // (H/2, 1024) half2 pairs along h
    const float* __restrict__ Wctx,     // (B*P, H)
    const float* __restrict__ walpha,   // (H)
    const float* __restrict__ hidden,   // (R,B,H)
    const float* __restrict__ lin_p,    // (H,H)
    const float* __restrict__ lin_x,    // (H,H)
    float* __restrict__ out_resp,       // (R,B,H)
    float* __restrict__ out_alpha,      // (R,W,B,P)
    float* __restrict__ w_glob,         // (64,4,1024) f32
    unsigned* __restrict__ atten_glob,  // (64,4,256) half2
    unsigned* __restrict__ cnt_a,       // 64
    unsigned* __restrict__ cnt_b)       // 64
{
    extern __shared__ float dynS[];
    float* sCtx   = dynS;                          // [32][512] 64 KB
    float* sWctx  = dynS + 16384;                  // [32][512] 64 KB
    float* sPart  = dynS + 32768;                  // [4][4][256] 16 KB (epilogue reuse)
    float* sW     = dynS + 36864;                  // [1024]     4 KB
    float* sAtten = dynS + 37888;                  // [512]      2 KB
    unsigned* sAttenH = (unsigned*)(dynS + 38400); // [4][256]   4 KB
    __shared__ float sWal[Hd];
    __shared__ float scS[Pd];

    const int bid = blockIdx.x;
    const int b_ = bid >> 2, j_ = bid & 3;
    const int tid = threadIdx.x;

    // ---- preamble: ctx[b], Wctx[b], walpha -> LDS ----
    for (int i = tid; i < 4096; i += 1024) {
        int p = i >> 7, h4 = (i & 127) << 2;
        *(float4*)&sCtx[(p << 9) + h4] =
            *(const float4*)&ctx[((size_t)(p * Bd + b_)) * Hd + h4];
        *(float4*)&sWctx[(p << 9) + h4] =
            *(const float4*)&Wctx[((size_t)(b_ * Pd + p)) * Hd + h4];
    }
    if (tid < Hd) sWal[tid] = walpha[tid];
    if (tid < 256) sAttenH[(j_ << 8) + tid] = 0u;
    __syncthreads();

    // ---- identities ----
    const int qid = tid >> 8;                 // h-quarter 0..3
    const int rr  = (tid >> 6) & 3;           // GEMM row 0..3
    const int c4  = (tid & 63) << 2;          // col quad within slice, 0..252
    const unsigned* __restrict__ wap =
        WAp + ((size_t)(qid << 6) << 10) + (j_ << 8) + c4;
    const int pB = tid >> 5, hcB = tid & 31;  // score: 32 threads per p

    unsigned tgt = 4u;
    for (int t = 0; t < Wd; ++t, tgt += 4u) {
        // rw prefetch for own row (consumed after sync1)
        float rwf = 0.f;
        if (tid < Hd) {
            unsigned short u = rwh[(((size_t)t * 256 + (j_ << 6) + b_) << 9) + tid];
            rwf = (float)__builtin_bit_cast(_Float16, u);
        }

        if (t > 0) {
            // fetch other rows' atten (published at end of t-1)
            if (tid < 768) {
                int rx = tid >> 8; rx += (rx >= j_) ? 1 : 0;
                sAttenH[(rx << 8) + (tid & 255)] =
                    atten_glob[(((b_ << 2) + rx) << 8) + (tid & 255)];
            }
            __syncthreads();

            // ---- GEMM: w[rr][slice j] over h-quarter qid ----
            float4 acc = make_float4(0.f, 0.f, 0.f, 0.f);
            const unsigned* __restrict__ ah = sAttenH + (rr << 8) + (qid << 6);
            #pragma unroll 4
            for (int jq = 0; jq < 16; ++jq) {
                const unsigned* wq = wap + ((size_t)jq << 12);
                uint4 w0 = *(const uint4*)(wq);
                uint4 w1 = *(const uint4*)(wq + 1024);
                uint4 w2 = *(const uint4*)(wq + 2048);
                uint4 w3 = *(const uint4*)(wq + 3072);
                uint4 a4 = *(const uint4*)(ah + (jq << 2));
                acc.x = d2(a4.x, w0.x, acc.x); acc.y = d2(a4.x, w0.y, acc.y);
                acc.z = d2(a4.x, w0.z, acc.z); acc.w = d2(a4.x, w0.w, acc.w);
                acc.x = d2(a4.y, w1.x, acc.x); acc.y = d2(a4.y, w1.y, acc.y);
                acc.z = d2(a4.y, w1.z, acc.z); acc.w = d2(a4.y, w1.w, acc.w);
                acc.x = d2(a4.z, w2.x, acc.x); acc.y = d2(a4.z, w2.y, acc.y);
                acc.z = d2(a4.z, w2.z, acc.z); acc.w = d2(a4.z, w2.w, acc.w);
                acc.x = d2(a4.w, w3.x, acc.x); acc.y = d2(a4.w, w3.y, acc.y);
                acc.z = d2(a4.w, w3.z, acc.z); acc.w = d2(a4.w, w3.w, acc.w);
            }
            *(float4*)&sPart[(((qid << 2) + rr) << 8) + c4] = acc;
            __syncthreads();

            // ---- reduce over h-quarters -> publish w slices ----
            {
                int r = tid >> 8, c = tid & 255;
                float s = sPart[((0 + r) << 8) + c] + sPart[((4 + r) << 8) + c]
                        + sPart[((8 + r) << 8) + c] + sPart[((12 + r) << 8) + c];
                w_glob[(((size_t)(b_ << 2) + r) << 10) + (j_ << 8) + c] = s;
            }
        }

        // ---- sync1: group w-exchange ----
        __syncthreads();
        if (tid == 0) {
            __threadfence();
            __hip_atomic_fetch_add(&cnt_a[b_], 1u, __ATOMIC_RELEASE, __HIP_MEMORY_SCOPE_AGENT);
            while (__hip_atomic_load(&cnt_a[b_], __ATOMIC_ACQUIRE, __HIP_MEMORY_SCOPE_AGENT) < tgt)
                __builtin_amdgcn_s_sleep(2);
            __threadfence();
        }
        __syncthreads();

        // ---- assemble own w row + rw ----
        if (t > 0) {
            float v = w_glob[(((size_t)(b_ << 2) + j_) << 10) + tid];
            if (tid < Hd) v += rwf;
            sW[tid] = v;
        } else {
            sW[tid] = (tid < Hd) ? rwf : 0.f;
        }
        __syncthreads();

        // ---- B: score[p] = sum_h tanh(Wctx[p,h]+w[h])*walpha[h] ----
        {
            const float* __restrict__ wrow = sWctx + (pB << 9);
            float sc = 0.f;
            #pragma unroll
            for (int k = 0; k < 4; ++k) {
                int h4 = (k << 7) + (hcB << 2);
                float4 wc  = *(const float4*)&wrow[h4];
                float4 wal = *(const float4*)&sWal[h4];
                float4 v   = *(const float4*)&sW[h4];
                sc += tanh_fast(wc.x+v.x)*wal.x + tanh_fast(wc.y+v.y)*wal.y
                    + tanh_fast(wc.z+v.z)*wal.z + tanh_fast(wc.w+v.w)*wal.w;
            }
            #pragma unroll
            for (int off = 16; off; off >>= 1) sc += __shfl_down(sc, off, 32);
            if (hcB == 0) scS[pB] = sc;
        }
        __syncthreads();

        // ---- C+D: softmax (in-register), alpha write, atten update for row j_ ----
        if (tid < Hd) {
            float sv[Pd];
            #pragma unroll
            for (int p = 0; p < Pd; ++p) sv[p] = scS[p];
            float m = sv[0];
            #pragma unroll
            for (int p = 1; p < Pd; ++p) m = fmaxf(m, sv[p]);
            float sum = 0.f;
            #pragma unroll
            for (int p = 0; p < Pd; ++p) { sv[p] = __expf(sv[p] - m); sum += sv[p]; }
            float inv = __fdividef(1.f, sum);
            if (tid < Pd)
                out_alpha[(((size_t)j_ * Wd + t) * Bd + b_) * Pd + tid] = sv[tid] * inv;
            float a = 0.f;
            #pragma unroll 8
            for (int p = 0; p < Pd; ++p) a += sv[p] * sCtx[(p << 9) + tid];
            a = a * inv + tanh_fast(sW[Hd + tid]);
            sAtten[tid] = a;
            float an = __shfl_down(a, 1, 64);
            if (!(tid & 1)) {
                unsigned ph = pk(a, an);
                sAttenH[(j_ << 8) + (tid >> 1)] = ph;
                atten_glob[(((b_ << 2) + j_) << 8) + (tid >> 1)] = ph;
            }
        }

        // ---- sync2: group atten-exchange ----
        __syncthreads();
        if (tid == 0) {
            __threadfence();
            __hip_atomic_fetch_add(&cnt_b[b_], 1u, __ATOMIC_RELEASE, __HIP_MEMORY_SCOPE_AGENT);
            while (__hip_atomic_load(&cnt_b[b_], __ATOMIC_ACQUIRE, __HIP_MEMORY_SCOPE_AGENT) < tgt)
                __builtin_amdgcn_s_sleep(2);
            __threadfence();
        }
        __syncthreads();
    }

    // ---- epilogue: resp_c row (r=j_, b_) = tanh(atten@lin_p^T + hidden@lin_x^T) ----
    if (tid < Hd) sPart[tid] = hidden[((size_t)(j_ * Bd + b_)) * Hd + tid];
    __syncthreads();
    {
        const int half = tid >> 9;
        const int c = tid & 511;
        const int hb = half << 8;
        const float* __restrict__ lp = lin_p + (size_t)c * Hd + hb;
        const float* __restrict__ lx = lin_x + (size_t)c * Hd + hb;
        float f = 0.f;
        #pragma unroll 2
        for (int h = 0; h < 256; h += 4) {
            float4 lpv = *(const float4*)(lp + h);
            float4 lxv = *(const float4*)(lx + h);
            float4 aa  = *(const float4*)&sAtten[hb + h];
            float4 hh  = *(const float4*)&sPart[hb + h];
            f += aa.x*lpv.x + aa.y*lpv.y + aa.z*lpv.z + aa.w*lpv.w
               + hh.x*lxv.x + hh.y*lxv.y + hh.z*lxv.z + hh.w*lxv.w;
        }
        sPart[1024 + (half << 9) + c] = f;
    }
    __syncthreads();
    if (tid < Hd) {
        float f = sPart[1024 + tid] + sPart[1536 + tid];
        out_resp[((size_t)(j_ * Bd + b_)) * Hd + tid] = tanh_fast(f);
    }
}

extern "C" void kernel_launch(void* const* d_in, const int* in_sizes, int n_in,
                              void* d_out, int out_size, void* d_ws, size_t ws_size,
                              hipStream_t stream) {
    const float* ctx    = (const float*)d_in[0];  // (P,B,H)
    const float* resp   = (const float*)d_in[1];  // (R,W,B,H)
    const float* hidden = (const float*)d_in[2];  // (R,B,H)
    const float* Wc     = (const float*)d_in[3];
    const float* Wt     = (const float*)d_in[4];
    const float* Wa     = (const float*)d_in[5];
    const float* Walpha = (const float*)d_in[6];  // (H,1)
    const float* lin_w  = (const float*)d_in[7];
    const float* lin_p  = (const float*)d_in[8];
    const float* lin_x  = (const float*)d_in[9];

    float* out = (float*)d_out;
    float* resp_c_out = out;                       // R*B*H
    float* alpha_out  = out + Rd * Bd * Hd;        // R*W*B*P

    float* ws = (float*)d_ws;
    unsigned* WAp = (unsigned*)ws;                          //   262144 u32 (1 MB)
    unsigned* Wtp = (unsigned*)(ws + 262144);               //   131072 u32 (0.5 MB)
    float* Wctx   = ws + 393216;                            //  1048576 f32 (4 MB)
    unsigned short* rwh = (unsigned short*)(ws + 1441792);  //  8388608 u16 (16 MB)
    float* w_glob = ws + 5636096;                           //   262144 f32 (1 MB)
    unsigned* atten_glob = (unsigned*)(ws + 5898240);       //    65536 u32 (256 KB)
    unsigned* cnt_a = (unsigned*)(ws + 5963776);            //    64 u32
    unsigned* cnt_b = cnt_a + 64;                           //    64 u32
    // total ~22.8 MB

    k_prep<<<dim3(16, 8), 256, 0, stream>>>(Wa, lin_w, Wt, WAp, Wtp);
    k_wctx<<<64, 256, 0, stream>>>(ctx, Wc, Wctx);
    k_rw<<<512, 512, 0, stream>>>(resp, Wtp, rwh);
    hipMemsetAsync(cnt_a, 0, 128 * sizeof(unsigned), stream);

    const int dyn_lds = 157696;
    static bool s_attr = false;
    if (!s_attr) {
        hipFuncSetAttribute((const void*)k_scan,
                            hipFuncAttributeMaxDynamicSharedMemorySize, dyn_lds);
        s_attr = true;
    }
    void* args[] = {
        (void*)&ctx, (void*)&rwh, (void*)&WAp, (void*)&Wctx, (void*)&Walpha,
        (void*)&hidden, (void*)&lin_p, (void*)&lin_x,
        (void*)&resp_c_out, (void*)&alpha_out,
        (void*)&w_glob, (void*)&atten_glob, (void*)&cnt_a, (void*)&cnt_b
    };
    hipLaunchCooperativeKernel((const void*)k_scan, dim3(256), dim3(1024),
                               args, dyn_lds, stream);
}

// Round 8
// 1381.020 us; speedup vs baseline: 2.4341x; 2.4341x over previous
//
#include <hip/hip_runtime.h>
#include <math.h>

#define Hd 512
#define Bd 64
#define Pd 32
#define Rd 4
#define Wd 64

typedef _Float16 h2v __attribute__((ext_vector_type(2)));

__device__ __forceinline__ float tanh_fast(float x) {
    float e = __expf(x + x);
    return 1.f - __fdividef(2.f, 1.f + e);
}

__device__ __forceinline__ float d2(unsigned a, unsigned b, float c) {
    return __builtin_amdgcn_fdot2(__builtin_bit_cast(h2v, a),
                                  __builtin_bit_cast(h2v, b), c, false);
}

__device__ __forceinline__ unsigned pk(float a, float b) {
    h2v p; p.x = (_Float16)a; p.y = (_Float16)b;
    return __builtin_bit_cast(unsigned, p);
}

// ---- build WAp = fp16-packed [W_a | lin_w^T] (256 h2 x 1024) + Wtp (256 h2 x 512) ----
// (proven in round 6)
__global__ __launch_bounds__(256) void k_prep(const float* __restrict__ Wa,
                                              const float* __restrict__ lin_w,
                                              const float* __restrict__ Wt,
                                              unsigned* __restrict__ WAp,
                                              unsigned* __restrict__ Wtp) {
    __shared__ unsigned tile[32][33];
    int bx = blockIdx.x, by = blockIdx.y;           // bx: 16 c-tiles, by: 8 h2-tiles
    int lane = threadIdx.x & 31, ty = threadIdx.x >> 5;
    for (int k = 0; k < 32; k += 8) {
        int h2 = by * 32 + ty + k, c = bx * 32 + lane;
        WAp[(size_t)h2 * 1024 + c] = pk(Wa[(size_t)(2 * h2) * Hd + c],
                                        Wa[(size_t)(2 * h2 + 1) * Hd + c]);
        Wtp[(size_t)h2 * 512 + c]  = pk(Wt[(size_t)(2 * h2) * Hd + c],
                                        Wt[(size_t)(2 * h2 + 1) * Hd + c]);
    }
    for (int k = 0; k < 32; k += 8) {
        int c_src = bx * 32 + ty + k, h2 = by * 32 + lane;
        float2 v = *(const float2*)&lin_w[(size_t)c_src * Hd + 2 * h2];
        tile[ty + k][lane] = pk(v.x, v.y);
    }
    __syncthreads();
    for (int k = 0; k < 32; k += 8) {
        int h2o = by * 32 + ty + k, co = bx * 32 + lane;
        WAp[(size_t)h2o * 1024 + 512 + co] = tile[lane][ty + k];
    }
}

// ---------------- Wctx[b,p,k] = sum_h ctx[b,p,h] * Wc[h,k]  (32 rows/block) ----------------
__global__ __launch_bounds__(256) void k_wctx(const float* __restrict__ ctx_pbh,
                                              const float* __restrict__ Wc,
                                              float* __restrict__ Wctx) {
    __shared__ float As[32][Hd];
    int r0 = blockIdx.x * 32;
    int tid = threadIdx.x;
    for (int rr = 0; rr < 32; ++rr) {
        int bp = r0 + rr;
        int b = bp >> 5, p = bp & 31;
        const float* src = ctx_pbh + ((size_t)p * Bd + b) * Hd;
        for (int h = tid; h < Hd; h += 256) As[rr][h] = src[h];
    }
    __syncthreads();
    int c0 = tid, c1 = tid + 256;
    float acc0[32], acc1[32];
    #pragma unroll
    for (int rr = 0; rr < 32; ++rr) { acc0[rr] = 0.f; acc1[rr] = 0.f; }
    for (int h = 0; h < Hd; ++h) {
        float w0 = Wc[(size_t)h * Hd + c0], w1 = Wc[(size_t)h * Hd + c1];
        #pragma unroll
        for (int rr = 0; rr < 32; ++rr) {
            float a = As[rr][h];
            acc0[rr] += a * w0;
            acc1[rr] += a * w1;
        }
    }
    for (int rr = 0; rr < 32; ++rr) {
        Wctx[(size_t)(r0 + rr) * Hd + c0] = acc0[rr];
        Wctx[(size_t)(r0 + rr) * Hd + c1] = acc1[rr];
    }
}

// ---------------- rwh[t*256+row][c] = fp16(sum_h resp * Wt), dot2 path (proven r6) ----------------
__global__ __launch_bounds__(512) void k_rw(const float* __restrict__ resp,
                                            const unsigned* __restrict__ Wtp,
                                            unsigned short* __restrict__ rwh) {
    __shared__ unsigned As[32 * 256];      // 32 rows x 256 h2, packed fp16
    int gr0 = blockIdx.x * 32, tid = threadIdx.x;
    for (int i = tid; i < 32 * 256; i += 512) {
        int rr = i >> 8, h2 = i & 255;
        int gr = gr0 + rr;
        int t = gr >> 8, row = gr & 255, r = row >> 6, bb = row & 63;
        float2 v = *(const float2*)(resp + (((size_t)(r * Wd + t)) * Bd + bb) * Hd + (h2 << 1));
        As[i] = pk(v.x, v.y);
    }
    __syncthreads();
    float acc[32];
    #pragma unroll
    for (int rr = 0; rr < 32; ++rr) acc[rr] = 0.f;
    const int c = tid;
    #pragma unroll 1
    for (int h2 = 0; h2 < 256; h2 += 4) {
        unsigned w0 = Wtp[((h2 + 0) << 9) + c];
        unsigned w1 = Wtp[((h2 + 1) << 9) + c];
        unsigned w2 = Wtp[((h2 + 2) << 9) + c];
        unsigned w3 = Wtp[((h2 + 3) << 9) + c];
        #pragma unroll
        for (int rr = 0; rr < 32; ++rr) {
            uint4 a4 = *(const uint4*)&As[(rr << 8) + h2];
            float s = acc[rr];
            s = d2(a4.x, w0, s); s = d2(a4.y, w1, s);
            s = d2(a4.z, w2, s); s = d2(a4.w, w3, s);
            acc[rr] = s;
        }
    }
    for (int rr = 0; rr < 32; ++rr)
        rwh[((size_t)(gr0 + rr) << 9) + c] =
            __builtin_bit_cast(unsigned short, (_Float16)acc[rr]);
}

// ---------------- persistent scan: 256 blocks (one per (r,b)), 1024 threads ----------------
// 3-phase, barrier-only sync, GEMV accumulates into sW via LDS atomicAdd:
//  P1 (all):   head GEMV (cols 0-511), upper half also zeroes sW tail.
//  P2 (split): waves 0-7 tail GEMV (cols 512-1023)  ||  waves 8-15 tanh-score.
//  P3 (split): waves 0-7 softmax+alpha+ctx-reduce+tanh(tail)+atten pack
//              ||  waves 8-15 pre-load rw(t+1) into sW head.
__global__ __launch_bounds__(1024, 4) void k_scan(
    const float* __restrict__ ctx,      // (P,B,H)
    const unsigned short* __restrict__ rwh, // (W*256, H) fp16
    const unsigned* __restrict__ WAp,   // (H/2, 1024) half2 pairs along h
    const float* __restrict__ Wctx,     // (B*P, H)
    const float* __restrict__ walpha,   // (H)
    const float* __restrict__ hidden,   // (R,B,H)
    const float* __restrict__ lin_p,    // (H,H)
    const float* __restrict__ lin_x,    // (H,H)
    float* __restrict__ out_resp,       // (R,B,H)
    float* __restrict__ out_alpha)      // (R,W,B,P)
{
    extern __shared__ float dynS[];
    float* sCtx   = dynS;                           // [32][512] 64 KB (persistent)
    float* sWctx  = dynS + 16384;                   // [32][512] 64 KB (persistent; epilogue scratch)
    float* sW     = dynS + 32768;                   // [1024]     4 KB
    float* sWal   = dynS + 33792;                   // [512]      2 KB
    float* sAtten = dynS + 34304;                   // [512]      2 KB (fp32, epilogue)
    float* scS    = dynS + 34816;                   // [32]
    unsigned* attenH = (unsigned*)(dynS + 34848);   // [256] half2 atten

    const int bid = blockIdx.x;
    const int r_ = bid >> 6, b_ = bid & 63;
    const int tid = threadIdx.x;
    const unsigned* rwU = (const unsigned*)rwh;

    // ---- preamble: ctx[b], Wctx[b], walpha -> LDS; sW head = rw(0); tail = 0 ----
    for (int i = tid; i < 4096; i += 1024) {
        int p = i >> 7, h4 = (i & 127) << 2;
        *(float4*)&sCtx[(p << 9) + h4] =
            *(const float4*)&ctx[((size_t)(p * Bd + b_)) * Hd + h4];
        *(float4*)&sWctx[(p << 9) + h4] =
            *(const float4*)&Wctx[((size_t)(b_ * Pd + p)) * Hd + h4];
    }
    if (tid < Hd) sWal[tid] = walpha[tid];
    if (tid < 256) {
        attenH[tid] = 0u;
        unsigned u = rwU[((size_t)(r_ * 64 + b_)) * 256 + tid];
        h2v hp = __builtin_bit_cast(h2v, u);
        sW[2 * tid]     = (float)hp.x;
        sW[2 * tid + 1] = (float)hp.y;
    }
    if (tid >= 512) sW[tid] = 0.f;
    __syncthreads();

    // ---- identities ----
    const int q1 = tid >> 8, pr = tid & 255;            // P1: h2-quarter, col-pair
    const int q3 = tid >> 7, qd = tid & 127;            // P2 gemv (tid<512): h2-quarter, col-quad
    const int pB = (tid - 512) >> 4, hc = (tid - 512) & 15; // P2 score (tid>=512)

    for (int t = 0; t < Wd; ++t) {
        // ================= P1: head GEMV (cols 0-511) =================
        {
            if (tid >= 512) sW[tid] = 0.f;     // zero tail for this step's P2 atomics
            float2 acc = make_float2(0.f, 0.f);
            const uint2* __restrict__ wp = (const uint2*)WAp + ((size_t)(q1 << 6)) * 512 + pr;
            const unsigned* __restrict__ ah = attenH + (q1 << 6);
            #pragma unroll 8
            for (int j = 0; j < 64; ++j) {
                uint2 wv = wp[(size_t)j * 512];
                unsigned av = ah[j];
                acc.x = d2(av, wv.x, acc.x);
                acc.y = d2(av, wv.y, acc.y);
            }
            atomicAdd(&sW[2 * pr],     acc.x);
            atomicAdd(&sW[2 * pr + 1], acc.y);
        }
        __syncthreads();   // B1: sW head complete

        // ================= P2: tail GEMV || tanh-score =================
        if (tid < 512) {
            float4 acc = make_float4(0.f, 0.f, 0.f, 0.f);
            const unsigned* __restrict__ wb = WAp + ((size_t)(q3 << 6)) * 1024 + 512 + (qd << 2);
            const unsigned* __restrict__ ah = attenH + (q3 << 6);
            #pragma unroll 8
            for (int j = 0; j < 64; ++j) {
                uint4 wv = *(const uint4*)(wb + (size_t)j * 1024);
                unsigned av = ah[j];
                acc.x = d2(av, wv.x, acc.x); acc.y = d2(av, wv.y, acc.y);
                acc.z = d2(av, wv.z, acc.z); acc.w = d2(av, wv.w, acc.w);
            }
            const int c = 512 + (qd << 2);
            atomicAdd(&sW[c],     acc.x); atomicAdd(&sW[c + 1], acc.y);
            atomicAdd(&sW[c + 2], acc.z); atomicAdd(&sW[c + 3], acc.w);
        } else {
            const float* __restrict__ wrow = sWctx + (pB << 9);
            float sc = 0.f;
            #pragma unroll
            for (int k = 0; k < 8; ++k) {
                int h4 = (hc << 2) + (k << 6);
                float4 wc = *(const float4*)&wrow[h4];
                float4 wl = *(const float4*)&sWal[h4];
                float4 v  = *(const float4*)&sW[h4];
                sc += tanh_fast(wc.x + v.x) * wl.x + tanh_fast(wc.y + v.y) * wl.y
                    + tanh_fast(wc.z + v.z) * wl.z + tanh_fast(wc.w + v.w) * wl.w;
            }
            sc += __shfl_down(sc, 8, 16);
            sc += __shfl_down(sc, 4, 16);
            sc += __shfl_down(sc, 2, 16);
            sc += __shfl_down(sc, 1, 16);
            if (hc == 0) scS[pB] = sc;
        }
        __syncthreads();   // B2: sW tail + scores complete

        // ================= P3: softmax + update || rw(t+1) preload =================
        if (tid < 512) {
            float sv[Pd];
            #pragma unroll
            for (int p = 0; p < Pd; ++p) sv[p] = scS[p];
            float m = sv[0];
            #pragma unroll
            for (int p = 1; p < Pd; ++p) m = fmaxf(m, sv[p]);
            float sum = 0.f;
            #pragma unroll
            for (int p = 0; p < Pd; ++p) { sv[p] = __expf(sv[p] - m); sum += sv[p]; }
            float inv = __fdividef(1.f, sum);
            if (tid < Pd)
                out_alpha[(((size_t)r_ * Wd + t) * Bd + b_) * Pd + tid] = sv[tid] * inv;
            float a = 0.f;
            #pragma unroll 8
            for (int p = 0; p < Pd; ++p) a += sv[p] * sCtx[(p << 9) + tid];
            a = a * inv + tanh_fast(sW[512 + tid]);
            sAtten[tid] = a;
            float an = __shfl_down(a, 1, 64);
            if (!(tid & 1)) attenH[tid >> 1] = pk(a, an);
        } else {
            const int tp = tid - 512;
            if (tp < 256 && t < Wd - 1) {
                unsigned u = rwU[((size_t)((t + 1) * 256 + r_ * 64 + b_)) * 256 + tp];
                h2v hp = __builtin_bit_cast(h2v, u);
                sW[2 * tp]     = (float)hp.x;
                sW[2 * tp + 1] = (float)hp.y;
            }
        }
        __syncthreads();   // B3: atten + next-step sW head ready
    }

    // ---- epilogue: resp_c = tanh(atten@lin_p^T + hidden@lin_x^T) ----
    if (tid < Hd) sWctx[tid] = hidden[((size_t)(r_ * Bd + b_)) * Hd + tid];
    __syncthreads();
    {
        const int half = tid >> 9;
        const int c = tid & 511;
        const int hb = half << 8;
        const float* __restrict__ lp = lin_p + (size_t)c * Hd + hb;
        const float* __restrict__ lx = lin_x + (size_t)c * Hd + hb;
        float f = 0.f;
        #pragma unroll 2
        for (int h = 0; h < 256; h += 4) {
            float4 lpv = *(const float4*)(lp + h);
            float4 lxv = *(const float4*)(lx + h);
            float4 aa  = *(const float4*)&sAtten[hb + h];
            float4 hh  = *(const float4*)&sWctx[hb + h];
            f += aa.x*lpv.x + aa.y*lpv.y + aa.z*lpv.z + aa.w*lpv.w
               + hh.x*lxv.x + hh.y*lxv.y + hh.z*lxv.z + hh.w*lxv.w;
        }
        sWctx[1024 + (half << 9) + c] = f;
    }
    __syncthreads();
    if (tid < Hd) {
        float f = sWctx[1024 + tid] + sWctx[1536 + tid];
        out_resp[((size_t)(r_ * Bd + b_)) * Hd + tid] = tanh_fast(f);
    }
}

extern "C" void kernel_launch(void* const* d_in, const int* in_sizes, int n_in,
                              void* d_out, int out_size, void* d_ws, size_t ws_size,
                              hipStream_t stream) {
    const float* ctx    = (const float*)d_in[0];  // (P,B,H)
    const float* resp   = (const float*)d_in[1];  // (R,W,B,H)
    const float* hidden = (const float*)d_in[2];  // (R,B,H)
    const float* Wc     = (const float*)d_in[3];
    const float* Wt     = (const float*)d_in[4];
    const float* Wa     = (const float*)d_in[5];
    const float* Walpha = (const float*)d_in[6];  // (H,1)
    const float* lin_w  = (const float*)d_in[7];
    const float* lin_p  = (const float*)d_in[8];
    const float* lin_x  = (const float*)d_in[9];

    float* out = (float*)d_out;
    float* resp_c_out = out;                       // R*B*H
    float* alpha_out  = out + Rd * Bd * Hd;        // R*W*B*P

    float* ws = (float*)d_ws;
    unsigned* WAp = (unsigned*)ws;                          //   262144 u32 (1 MB)
    unsigned* Wtp = (unsigned*)(ws + 262144);               //   131072 u32 (0.5 MB)
    float* Wctx   = ws + 393216;                            //  1048576 f32 (4 MB)
    unsigned short* rwh = (unsigned short*)(ws + 1441792);  //  8388608 u16 (16 MB)
    // total ~21.5 MB

    k_prep<<<dim3(16, 8), 256, 0, stream>>>(Wa, lin_w, Wt, WAp, Wtp);
    k_wctx<<<64, 256, 0, stream>>>(ctx, Wc, Wctx);
    k_rw<<<512, 512, 0, stream>>>(resp, Wtp, rwh);

    const int dyn_lds = 140416;                    // 35104 floats (~137 KB)
    static bool s_attr = false;
    if (!s_attr) {
        hipFuncSetAttribute((const void*)k_scan,
                            hipFuncAttributeMaxDynamicSharedMemorySize, dyn_lds);
        s_attr = true;
    }
    k_scan<<<256, 1024, dyn_lds, stream>>>(ctx, rwh, WAp, Wctx, Walpha, hidden,
                                           lin_p, lin_x, resp_c_out, alpha_out);
}